// Round 19
// baseline (3286.362 us; speedup 1.0000x reference)
//
#include <hip/hip_runtime.h>
#include <stdint.h>

// LSTM(relu) persistent kernel v19: B=64,S=1024,F=128,H=512.
// = v17 (best, 2459us: tagged-data single-hop sync — h>=0 so bf16 sign bit
// carries the generation marker; producer stores ONE u64/row; consumer spins
// on exactly the u64s it needs (poll IS the data); XCD-local groups via
// HW_REG_XCC_ID; LDS [U;W]^T stride 648; 4-wave K-split; single barrier + R
// staging; direct out store) with ONE change:
//   SOFTWARE-PIPELINED DOUBLE-BUFFERED POLL. v17's loop issued 8 loads and
//   waited vmcnt(0) before checking -> each sample costs a full memory RT
//   (~800cy); a publish landing mid-iteration waits up to a full RT before
//   detection. Now two batches rotate: issue B, check A (compiler waits
//   vmcnt(8) = only A, in-order retirement), issue A, check B, ... ->
//   sampling interval ~max(check, RT/2) instead of RT. (v18's LDS out-buffer
//   reverted: regression.)
// 256 wgs x 256 thr, ~99KB LDS -> exactly 1 wg/CU (XCD pigeonhole intact).

#define S_ 1024
#define F_ 128
#define H_ 512
#define G4_ 2048
#define KH 16           // h@U K-steps (512/32)
#define KDIM 640
#define LDKS 648        // padded LDS stride (shorts)
#define HB (64 * H_)    // one h buffer: 64 rows x 512 units (bf16, sign=marker)
#define SMASK8 0x8000800080008000ull
#define VMASK8 0x7FFF7FFF7FFF7FFFull

typedef __attribute__((ext_vector_type(8))) short short8;  // 8 x bf16
typedef __attribute__((ext_vector_type(4))) float f32x4;
typedef unsigned long long ull;

__device__ __forceinline__ unsigned short f2bf(float f) {
  union { float f; unsigned u; } v; v.f = f;
  unsigned u = v.u + 0x7fffu + ((v.u >> 16) & 1u);   // RNE
  return (unsigned short)(u >> 16);
}

__device__ __forceinline__ short8 pack2(f32x4 a, f32x4 b) {
  short8 r;
#pragma unroll
  for (int i = 0; i < 4; ++i) r[i] = (short)f2bf(a[i]);
#pragma unroll
  for (int i = 0; i < 4; ++i) r[4 + i] = (short)f2bf(b[i]);
  return r;
}

__global__ __launch_bounds__(256, 1) void lstm_pers(
    const float* __restrict__ x, const float* __restrict__ W,
    const float* __restrict__ U, const float* __restrict__ bias,
    float* __restrict__ out, unsigned int* ws_sync, unsigned short* hbuf) {

  __shared__ unsigned short V[64 * LDKS];   // 82944 B
  __shared__ f32x4 R[4][4][64];             // 16384 B partial staging
  __shared__ int meta[2];

  const int tid  = threadIdx.x;
  const int w    = tid >> 6;           // wave 0..3 (k-steps 4w..4w+3; tile w)
  const int lane = tid & 63;
  const int l15  = lane & 15;
  const int l4   = lane >> 4;
  const int koff = l4 * 8;

  // ---- physical XCD id + slot claim (robust group formation) ----
  if (tid == 0) {
    unsigned int xcc;
    asm volatile("s_getreg_b32 %0, hwreg(20, 0, 4)" : "=s"(xcc));  // HW_REG_XCC_ID
    xcc &= 7;
    unsigned sv = atomicAdd(ws_sync + xcc * 32, 1u);   // 128B-spaced ctrs
    meta[0] = (int)xcc;
    meta[1] = (int)(sv & 31);
  }
  __syncthreads();
  const int xcc  = meta[0];
  const int slot = meta[1];

  const int u0    = slot * 16;       // 16 units per wg
  const int bbase = xcc * 8;         // 8 batch rows per group

  // ---- LDS fill (validated decomposition, stride 648) ----
  for (int idx = tid; idx < (64 * KDIM) / 4; idx += 256) {
    const int q4   = idx & 15;
    const int k    = idx >> 4;                // 0..639
    const int gate = q4 & 3;
    const int ul0  = (q4 >> 2) * 4;           // 0,4,8,12
    const int col  = gate * H_ + u0 + ul0;
    const float* src = (k < H_) ? (U + (size_t)k * G4_ + col)
                                : (W + (size_t)(k - H_) * G4_ + col);
    const f32x4 v4 = *(const f32x4*)src;
#pragma unroll
    for (int q = 0; q < 4; ++q) {
      const int ul = ul0 + q;
      const int cc = (ul >> 2) * 16 + (ul & 3) * 4 + gate;
      V[cc * LDKS + k] = f2bf(v4[q]);
    }
  }

  // wave w's gate bias for tile w: unit = u0 + w*4 + l4
  float bias_r[4];
#pragma unroll
  for (int g = 0; g < 4; ++g) bias_r[g] = bias[g * H_ + u0 + w * 4 + l4];

  __syncthreads();

  const int brow = bbase + (l15 & 7);   // rows duplicated for l15>=8
  const float* xrow = x + (size_t)brow * S_ * F_ + koff + w * 32;
  const unsigned short* hrow0 = hbuf + (size_t)brow * H_ + koff;
  const int myunit = u0 + w * 4 + l4;   // this lane's (row,unit) in tile w

  float cst = 0.f;                      // c-state of (brow, myunit)

  // preload x(0) slice for this wave
  f32x4 xa = *(const f32x4*)(xrow);
  f32x4 xb = *(const f32x4*)(xrow + 4);

  for (int t = 0; t < S_; ++t) {
    // ---- x @ W first (h-independent): hides the data-poll below ----
    f32x4 acc[4];
#pragma unroll
    for (int tl = 0; tl < 4; ++tl) { acc[tl][0]=0.f; acc[tl][1]=0.f; acc[tl][2]=0.f; acc[tl][3]=0.f; }
    {
      const short8 bx = pack2(xa, xb);
      const int k0 = (KH + w) * 32 + koff;
#pragma unroll
      for (int tl = 0; tl < 4; ++tl) {
        const short8 a = *(const short8*)&V[(tl * 16 + l15) * LDKS + k0];
        acc[tl] = __builtin_amdgcn_mfma_f32_16x16x32_bf16(a, bx, acc[tl], 0, 0, 0);
      }
    }

    // ---- issue x(t+1) loads now; they complete under h@U ----
    {
      const int tn = (t + 1 < S_) ? t + 1 : t;
      const float* xt = xrow + (size_t)tn * F_;
      xa = *(const f32x4*)(xt);
      xb = *(const f32x4*)(xt + 4);
    }

    // ---- tagged data-poll, DOUBLE-BUFFERED: check batch A while batch B
    //      flies (vmcnt(8) waits only for the older batch) ----
    if (t > 0) {
      const ull expm = (((((unsigned)(t - 1)) >> 1) & 1u) ^ 1u) ? SMASK8 : 0ull;
      const unsigned short* hr = hrow0 + (size_t)(t & 1) * HB;
      const ull* q0 = (const ull*)(hr + (4 * w + 0) * 32);
      const ull* q1 = (const ull*)(hr + (4 * w + 1) * 32);
      const ull* q2 = (const ull*)(hr + (4 * w + 2) * 32);
      const ull* q3 = (const ull*)(hr + (4 * w + 3) * 32);

      ull A[8], Bt[8], D[8];
#define LOAD8(dst)                                                                      \
      do {                                                                              \
        dst[0] = __hip_atomic_load(q0,     __ATOMIC_RELAXED, __HIP_MEMORY_SCOPE_AGENT); \
        dst[1] = __hip_atomic_load(q0 + 1, __ATOMIC_RELAXED, __HIP_MEMORY_SCOPE_AGENT); \
        dst[2] = __hip_atomic_load(q1,     __ATOMIC_RELAXED, __HIP_MEMORY_SCOPE_AGENT); \
        dst[3] = __hip_atomic_load(q1 + 1, __ATOMIC_RELAXED, __HIP_MEMORY_SCOPE_AGENT); \
        dst[4] = __hip_atomic_load(q2,     __ATOMIC_RELAXED, __HIP_MEMORY_SCOPE_AGENT); \
        dst[5] = __hip_atomic_load(q2 + 1, __ATOMIC_RELAXED, __HIP_MEMORY_SCOPE_AGENT); \
        dst[6] = __hip_atomic_load(q3,     __ATOMIC_RELAXED, __HIP_MEMORY_SCOPE_AGENT); \
        dst[7] = __hip_atomic_load(q3 + 1, __ATOMIC_RELAXED, __HIP_MEMORY_SCOPE_AGENT); \
      } while (0)
#define CHECK8(src, okv)                                                                \
      do {                                                                              \
        const ull bad = (src[0] ^ expm) | (src[1] ^ expm) | (src[2] ^ expm) |           \
                        (src[3] ^ expm) | (src[4] ^ expm) | (src[5] ^ expm) |           \
                        (src[6] ^ expm) | (src[7] ^ expm);                              \
        okv = __all((int)((bad & SMASK8) == 0ull));                                     \
      } while (0)

      LOAD8(A);
      while (true) {
        int ok;
        LOAD8(Bt);            // in flight while we check A
        CHECK8(A, ok);
        if (ok) {
#pragma unroll
          for (int i = 0; i < 8; ++i) D[i] = A[i];
          break;
        }
        LOAD8(A);             // in flight while we check B
        CHECK8(Bt, ok);
        if (ok) {
#pragma unroll
          for (int i = 0; i < 8; ++i) D[i] = Bt[i];
          break;
        }
      }
#undef LOAD8
#undef CHECK8

      // strip markers -> B-frags -> h@U MFMAs
      union { ull u[2]; short8 s; } b0, b1, b2, b3;
      b0.u[0] = D[0] & VMASK8; b0.u[1] = D[1] & VMASK8;
      b1.u[0] = D[2] & VMASK8; b1.u[1] = D[3] & VMASK8;
      b2.u[0] = D[4] & VMASK8; b2.u[1] = D[5] & VMASK8;
      b3.u[0] = D[6] & VMASK8; b3.u[1] = D[7] & VMASK8;
      const short8 bh[4] = {b0.s, b1.s, b2.s, b3.s};
#pragma unroll
      for (int i = 0; i < 4; ++i) {
        const int k0 = (4 * w + i) * 32 + koff;
#pragma unroll
        for (int tl = 0; tl < 4; ++tl) {
          const short8 a = *(const short8*)&V[(tl * 16 + l15) * LDKS + k0];
          acc[tl] = __builtin_amdgcn_mfma_f32_16x16x32_bf16(a, bh[i], acc[tl], 0, 0, 0);
        }
      }
    }

    // ---- stage partials; barrier (reduce sync + publish gate: union of
    //      the 4 waves' data-polls = all 32 slots at gen t-1) ----
#pragma unroll
    for (int tl = 0; tl < 4; ++tl) R[w][tl][lane] = acc[tl];
    __syncthreads();
    // single-buffered R safe: read(t) < barrier(t) < poll(t+1) < write(t+1).

    f32x4 z;
    {
      const f32x4 r0 = R[0][w][lane], r1 = R[1][w][lane],
                  r2 = R[2][w][lane], r3 = R[3][w][lane];
#pragma unroll
      for (int g = 0; g < 4; ++g)
        z[g] = bias_r[g] + r0[g] + r1[g] + r2[g] + r3[g];
    }

    // ---- gates for (brow, myunit) ----
    const float ig = 1.f / (1.f + __expf(-z[0]));
    const float fg = 1.f / (1.f + __expf(-z[1]));
    const float gg = fmaxf(z[2], 0.f);             // relu candidate
    const float og = 1.f / (1.f + __expf(-z[3]));
    const float cn = fg * cst + ig * gg;
    cst = cn;
    const float hv = og * fmaxf(cn, 0.f);          // relu output (>= 0)

    // ---- gather row's 4 units -> ONE tagged u64 per row; store = sync ----
    const unsigned hb0 = (unsigned)f2bf(hv);
    const unsigned hb1 = (unsigned)__shfl((int)hb0, (lane & 7) + 16);
    const unsigned hb2 = (unsigned)__shfl((int)hb0, (lane & 7) + 32);
    const unsigned hb3 = (unsigned)__shfl((int)hb0, (lane & 7) + 48);
    const ull tagw = ((((unsigned)t >> 1) & 1u) ^ 1u) ? SMASK8 : 0ull;
    const ull wrd = (ull)(hb0 & 0xFFFFu) | ((ull)(hb1 & 0xFFFFu) << 16) |
                    ((ull)(hb2 & 0xFFFFu) << 32) | ((ull)(hb3 & 0xFFFFu) << 48) | tagw;
    if (lane < 8) {
      ull* dst = (ull*)(hbuf + (size_t)((t + 1) & 1) * HB +
                        (size_t)(bbase + lane) * H_ + u0 + w * 4);
      __hip_atomic_store(dst, wrd, __ATOMIC_RELAXED, __HIP_MEMORY_SCOPE_AGENT);
    }

    if (l15 < 8)
      out[((size_t)brow * S_ + t) * H_ + myunit] = hv;   // off the publish path
  }
}

extern "C" void kernel_launch(void* const* d_in, const int* in_sizes, int n_in,
                              void* d_out, int out_size, void* d_ws, size_t ws_size,
                              hipStream_t stream) {
  const float* x = (const float*)d_in[0];
  const float* W = (const float*)d_in[1];
  const float* U = (const float*)d_in[2];
  const float* b = (const float*)d_in[3];
  float* out = (float*)d_out;

  unsigned int*   ws_sync = (unsigned int*)d_ws;                   // slot ctrs (1KB)
  unsigned short* hbuf    = (unsigned short*)((char*)d_ws + 1024); // 2 x 64 x 512 bf16 = 128KB

  // zero ctrs + BOTH tagged h buffers (markers must start invalid = 0)
  hipMemsetAsync(d_ws, 0, 1024 + 2 * HB * sizeof(unsigned short), stream);

  lstm_pers<<<dim3(256), dim3(256), 0, stream>>>(x, W, U, b, out, ws_sync, hbuf);
}

// Round 20
// 2449.415 us; speedup vs baseline: 1.3417x; 1.3417x over previous
//
#include <hip/hip_runtime.h>
#include <stdint.h>

// LSTM(relu) persistent kernel v20 = v17 (best, 2459us), restored verbatim.
// Structure: XCD-local groups via HW_REG_XCC_ID (8 groups x 8 batch rows, one
// per XCD; 32 wgs/group claim slots via atomicAdd); LDS-resident [U;W]^T bf16
// (stride 648); 4-wave K-split per wg (wave w: h-k-steps 4w..4w+3 + x-k-step
// w; tile w epilogue); single barrier + R staging per step.
// Sync: SINGLE-HOP TAGGED-DATA. h >= 0 (sigmoid*relu) -> bf16 sign bit is a
// free generation marker ((t>>1)&1)^1. Producer wave gathers each row's 4
// units (3 shuffles) and stores ONE u64/row (atomic AGENT, relaxed); consumer
// wave spins directly on the 8 u64s it needs: the poll IS the data (one
// memory RT on the critical path; no flags, no vmcnt drain).
// Overwrite safety: wave w's poll covers slots 8w..8w+7; union over 4 waves =
// all 32 slots; publish is after the barrier -> publish(t) proves all wgs
// finished reading gen t-2 (the buffer being overwritten). Marker alternates
// every 2 steps -> distinguishes gen t-1 / t-3 / zeroed-init.
// 19-round conclusion: 6 distinct protocols converge at 2.46-2.73ms; floor =
// 1024 x (publish-visibility RT + detect-under-contention + compute tail).
// Counters show no pipe saturated (MfmaUtil ~5%, HBM ~2%) - latency-bound.
// 256 wgs x 256 thr, ~99KB LDS -> exactly 1 wg/CU (XCD pigeonhole intact).

#define S_ 1024
#define F_ 128
#define H_ 512
#define G4_ 2048
#define KH 16           // h@U K-steps (512/32)
#define KDIM 640
#define LDKS 648        // padded LDS stride (shorts)
#define HB (64 * H_)    // one h buffer: 64 rows x 512 units (bf16, sign=marker)
#define SMASK8 0x8000800080008000ull
#define VMASK8 0x7FFF7FFF7FFF7FFFull

typedef __attribute__((ext_vector_type(8))) short short8;  // 8 x bf16
typedef __attribute__((ext_vector_type(4))) float f32x4;
typedef unsigned long long ull;

__device__ __forceinline__ unsigned short f2bf(float f) {
  union { float f; unsigned u; } v; v.f = f;
  unsigned u = v.u + 0x7fffu + ((v.u >> 16) & 1u);   // RNE
  return (unsigned short)(u >> 16);
}

__device__ __forceinline__ short8 pack2(f32x4 a, f32x4 b) {
  short8 r;
#pragma unroll
  for (int i = 0; i < 4; ++i) r[i] = (short)f2bf(a[i]);
#pragma unroll
  for (int i = 0; i < 4; ++i) r[4 + i] = (short)f2bf(b[i]);
  return r;
}

__global__ __launch_bounds__(256, 1) void lstm_pers(
    const float* __restrict__ x, const float* __restrict__ W,
    const float* __restrict__ U, const float* __restrict__ bias,
    float* __restrict__ out, unsigned int* ws_sync, unsigned short* hbuf) {

  __shared__ unsigned short V[64 * LDKS];   // 82944 B
  __shared__ f32x4 R[4][4][64];             // 16384 B partial staging
  __shared__ int meta[2];

  const int tid  = threadIdx.x;
  const int w    = tid >> 6;           // wave 0..3 (k-steps 4w..4w+3; tile w)
  const int lane = tid & 63;
  const int l15  = lane & 15;
  const int l4   = lane >> 4;
  const int koff = l4 * 8;

  // ---- physical XCD id + slot claim (robust group formation) ----
  if (tid == 0) {
    unsigned int xcc;
    asm volatile("s_getreg_b32 %0, hwreg(20, 0, 4)" : "=s"(xcc));  // HW_REG_XCC_ID
    xcc &= 7;
    unsigned sv = atomicAdd(ws_sync + xcc * 32, 1u);   // 128B-spaced ctrs
    meta[0] = (int)xcc;
    meta[1] = (int)(sv & 31);
  }
  __syncthreads();
  const int xcc  = meta[0];
  const int slot = meta[1];

  const int u0    = slot * 16;       // 16 units per wg
  const int bbase = xcc * 8;         // 8 batch rows per group

  // ---- LDS fill (validated decomposition, stride 648) ----
  for (int idx = tid; idx < (64 * KDIM) / 4; idx += 256) {
    const int q4   = idx & 15;
    const int k    = idx >> 4;                // 0..639
    const int gate = q4 & 3;
    const int ul0  = (q4 >> 2) * 4;           // 0,4,8,12
    const int col  = gate * H_ + u0 + ul0;
    const float* src = (k < H_) ? (U + (size_t)k * G4_ + col)
                                : (W + (size_t)(k - H_) * G4_ + col);
    const f32x4 v4 = *(const f32x4*)src;
#pragma unroll
    for (int q = 0; q < 4; ++q) {
      const int ul = ul0 + q;
      const int cc = (ul >> 2) * 16 + (ul & 3) * 4 + gate;
      V[cc * LDKS + k] = f2bf(v4[q]);
    }
  }

  // wave w's gate bias for tile w: unit = u0 + w*4 + l4
  float bias_r[4];
#pragma unroll
  for (int g = 0; g < 4; ++g) bias_r[g] = bias[g * H_ + u0 + w * 4 + l4];

  __syncthreads();

  const int brow = bbase + (l15 & 7);   // rows duplicated for l15>=8
  const float* xrow = x + (size_t)brow * S_ * F_ + koff + w * 32;
  const unsigned short* hrow0 = hbuf + (size_t)brow * H_ + koff;
  const int myunit = u0 + w * 4 + l4;   // this lane's (row,unit) in tile w

  float cst = 0.f;                      // c-state of (brow, myunit)

  // preload x(0) slice for this wave
  f32x4 xa = *(const f32x4*)(xrow);
  f32x4 xb = *(const f32x4*)(xrow + 4);

  for (int t = 0; t < S_; ++t) {
    // ---- x @ W first (h-independent): hides the data-poll below ----
    f32x4 acc[4];
#pragma unroll
    for (int tl = 0; tl < 4; ++tl) { acc[tl][0]=0.f; acc[tl][1]=0.f; acc[tl][2]=0.f; acc[tl][3]=0.f; }
    {
      const short8 bx = pack2(xa, xb);
      const int k0 = (KH + w) * 32 + koff;
#pragma unroll
      for (int tl = 0; tl < 4; ++tl) {
        const short8 a = *(const short8*)&V[(tl * 16 + l15) * LDKS + k0];
        acc[tl] = __builtin_amdgcn_mfma_f32_16x16x32_bf16(a, bx, acc[tl], 0, 0, 0);
      }
    }

    // ---- issue x(t+1) loads now; they complete under h@U ----
    {
      const int tn = (t + 1 < S_) ? t + 1 : t;
      const float* xt = xrow + (size_t)tn * F_;
      xa = *(const f32x4*)(xt);
      xb = *(const f32x4*)(xt + 4);
    }

    // ---- tagged data-poll of MY 4 h k-steps: poll IS the data ----
    if (t > 0) {
      const ull expm = (((((unsigned)(t - 1)) >> 1) & 1u) ^ 1u) ? SMASK8 : 0ull;
      const unsigned short* hr = hrow0 + (size_t)(t & 1) * HB;
      const ull* q0 = (const ull*)(hr + (4 * w + 0) * 32);
      const ull* q1 = (const ull*)(hr + (4 * w + 1) * 32);
      const ull* q2 = (const ull*)(hr + (4 * w + 2) * 32);
      const ull* q3 = (const ull*)(hr + (4 * w + 3) * 32);
      ull d0, d1, d2, d3, d4, d5, d6, d7;
      while (true) {
        d0 = __hip_atomic_load(q0,     __ATOMIC_RELAXED, __HIP_MEMORY_SCOPE_AGENT);
        d1 = __hip_atomic_load(q0 + 1, __ATOMIC_RELAXED, __HIP_MEMORY_SCOPE_AGENT);
        d2 = __hip_atomic_load(q1,     __ATOMIC_RELAXED, __HIP_MEMORY_SCOPE_AGENT);
        d3 = __hip_atomic_load(q1 + 1, __ATOMIC_RELAXED, __HIP_MEMORY_SCOPE_AGENT);
        d4 = __hip_atomic_load(q2,     __ATOMIC_RELAXED, __HIP_MEMORY_SCOPE_AGENT);
        d5 = __hip_atomic_load(q2 + 1, __ATOMIC_RELAXED, __HIP_MEMORY_SCOPE_AGENT);
        d6 = __hip_atomic_load(q3,     __ATOMIC_RELAXED, __HIP_MEMORY_SCOPE_AGENT);
        d7 = __hip_atomic_load(q3 + 1, __ATOMIC_RELAXED, __HIP_MEMORY_SCOPE_AGENT);
        const ull bad = (d0 ^ expm) | (d1 ^ expm) | (d2 ^ expm) | (d3 ^ expm) |
                        (d4 ^ expm) | (d5 ^ expm) | (d6 ^ expm) | (d7 ^ expm);
        if (__all((int)((bad & SMASK8) == 0ull))) break;
      }
      // strip markers -> B-frags -> h@U MFMAs
      union { ull u[2]; short8 s; } b0, b1, b2, b3;
      b0.u[0] = d0 & VMASK8; b0.u[1] = d1 & VMASK8;
      b1.u[0] = d2 & VMASK8; b1.u[1] = d3 & VMASK8;
      b2.u[0] = d4 & VMASK8; b2.u[1] = d5 & VMASK8;
      b3.u[0] = d6 & VMASK8; b3.u[1] = d7 & VMASK8;
      const short8 bh[4] = {b0.s, b1.s, b2.s, b3.s};
#pragma unroll
      for (int i = 0; i < 4; ++i) {
        const int k0 = (4 * w + i) * 32 + koff;
#pragma unroll
        for (int tl = 0; tl < 4; ++tl) {
          const short8 a = *(const short8*)&V[(tl * 16 + l15) * LDKS + k0];
          acc[tl] = __builtin_amdgcn_mfma_f32_16x16x32_bf16(a, bh[i], acc[tl], 0, 0, 0);
        }
      }
    }

    // ---- stage partials; barrier (reduce sync + publish gate: union of
    //      the 4 waves' data-polls = all 32 slots at gen t-1) ----
#pragma unroll
    for (int tl = 0; tl < 4; ++tl) R[w][tl][lane] = acc[tl];
    __syncthreads();
    // single-buffered R safe: read(t) < barrier(t) < poll(t+1) < write(t+1).

    f32x4 z;
    {
      const f32x4 r0 = R[0][w][lane], r1 = R[1][w][lane],
                  r2 = R[2][w][lane], r3 = R[3][w][lane];
#pragma unroll
      for (int g = 0; g < 4; ++g)
        z[g] = bias_r[g] + r0[g] + r1[g] + r2[g] + r3[g];
    }

    // ---- gates for (brow, myunit) ----
    const float ig = 1.f / (1.f + __expf(-z[0]));
    const float fg = 1.f / (1.f + __expf(-z[1]));
    const float gg = fmaxf(z[2], 0.f);             // relu candidate
    const float og = 1.f / (1.f + __expf(-z[3]));
    const float cn = fg * cst + ig * gg;
    cst = cn;
    const float hv = og * fmaxf(cn, 0.f);          // relu output (>= 0)

    // ---- gather row's 4 units -> ONE tagged u64 per row; store = sync ----
    const unsigned hb0 = (unsigned)f2bf(hv);
    const unsigned hb1 = (unsigned)__shfl((int)hb0, (lane & 7) + 16);
    const unsigned hb2 = (unsigned)__shfl((int)hb0, (lane & 7) + 32);
    const unsigned hb3 = (unsigned)__shfl((int)hb0, (lane & 7) + 48);
    const ull tagw = ((((unsigned)t >> 1) & 1u) ^ 1u) ? SMASK8 : 0ull;
    const ull wrd = (ull)(hb0 & 0xFFFFu) | ((ull)(hb1 & 0xFFFFu) << 16) |
                    ((ull)(hb2 & 0xFFFFu) << 32) | ((ull)(hb3 & 0xFFFFu) << 48) | tagw;
    if (lane < 8) {
      ull* dst = (ull*)(hbuf + (size_t)((t + 1) & 1) * HB +
                        (size_t)(bbase + lane) * H_ + u0 + w * 4);
      __hip_atomic_store(dst, wrd, __ATOMIC_RELAXED, __HIP_MEMORY_SCOPE_AGENT);
    }

    if (l15 < 8)
      out[((size_t)brow * S_ + t) * H_ + myunit] = hv;   // off the publish path
  }
}

extern "C" void kernel_launch(void* const* d_in, const int* in_sizes, int n_in,
                              void* d_out, int out_size, void* d_ws, size_t ws_size,
                              hipStream_t stream) {
  const float* x = (const float*)d_in[0];
  const float* W = (const float*)d_in[1];
  const float* U = (const float*)d_in[2];
  const float* b = (const float*)d_in[3];
  float* out = (float*)d_out;

  unsigned int*   ws_sync = (unsigned int*)d_ws;                   // slot ctrs (1KB)
  unsigned short* hbuf    = (unsigned short*)((char*)d_ws + 1024); // 2 x 64 x 512 bf16 = 128KB

  // zero ctrs + BOTH tagged h buffers (markers must start invalid = 0)
  hipMemsetAsync(d_ws, 0, 1024 + 2 * HB * sizeof(unsigned short), stream);

  lstm_pers<<<dim3(256), dim3(256), 0, stream>>>(x, W, U, b, out, ws_sync, hbuf);
}